// Round 7
// baseline (264.281 us; speedup 1.0000x reference)
//
#include <hip/hip_runtime.h>
#include <hip/hip_bf16.h>
#include <math.h>

#define DIMX   1024
#define HEADS  16
#define DH     64
#define NB     8
#define NSEQ   1024
#define ROWS   (NB * NSEQ)        // 8192
#define QKVW   (3 * DIMX)         // 3072
#define LOG2E  1.44269504088896f

typedef _Float16 half8 __attribute__((ext_vector_type(8)));
typedef _Float16 half4 __attribute__((ext_vector_type(4)));
typedef float floatx4 __attribute__((ext_vector_type(4)));

// async global->LDS, 16B per lane. lptr must be wave-uniform; HW adds lane*16.
#define GLD_LDS16(gptr, lptr) __builtin_amdgcn_global_load_lds( \
    (const __attribute__((address_space(1))) void*)(gptr),      \
    (__attribute__((address_space(3))) void*)(lptr), 16, 0, 0)

__device__ __forceinline__ float fexp2(float x) {
#if __has_builtin(__builtin_amdgcn_exp2f)
    return __builtin_amdgcn_exp2f(x);
#else
    return __expf(x * 0.69314718056f);
#endif
}

// ---------------------------------------------------------------------------
// Kernel 1: merged LayerNorm (blocks 0..8191) + weight transpose (8192..12287)
// ---------------------------------------------------------------------------
__global__ __launch_bounds__(256) void lnw_kernel(const float* __restrict__ x,
                                                  const float* __restrict__ gamma,
                                                  const float* __restrict__ Wq,
                                                  const float* __restrict__ Wo,
                                                  _Float16* __restrict__ xn,
                                                  _Float16* __restrict__ WqT,
                                                  _Float16* __restrict__ WoT) {
    __shared__ float tile[32][33];
    __shared__ float sbuf[4], ssbuf[4];
    int t = threadIdx.x;

    if (blockIdx.x < ROWS) {
        int row = blockIdx.x;
        const float* xr = x + (size_t)row * DIMX;
        _Float16* xo = xn + (size_t)row * DIMX;

        float4 v = ((const float4*)xr)[t];
        float s  = v.x + v.y + v.z + v.w;
        float ss = v.x*v.x + v.y*v.y + v.z*v.z + v.w*v.w;
        #pragma unroll
        for (int o = 32; o > 0; o >>= 1) {
            s  += __shfl_down(s, o);
            ss += __shfl_down(ss, o);
        }
        int lane = t & 63, wid = t >> 6;
        if (lane == 0) { sbuf[wid] = s; ssbuf[wid] = ss; }
        __syncthreads();
        if (t == 0) {
            float a = 0.f, b2 = 0.f;
            for (int i = 0; i < 4; i++) { a += sbuf[i]; b2 += ssbuf[i]; }
            sbuf[0] = a; ssbuf[0] = b2;
        }
        __syncthreads();
        float mean = sbuf[0] * (1.0f / DIMX);
        float var  = ssbuf[0] * (1.0f / DIMX) - mean * mean;
        float rstd = rsqrtf(var + 1e-5f);

        float4 g = ((const float4*)gamma)[t];
        half4 o;
        o.x = (_Float16)((v.x - mean) * rstd * g.x);
        o.y = (_Float16)((v.y - mean) * rstd * g.y);
        o.z = (_Float16)((v.z - mean) * rstd * g.z);
        o.w = (_Float16)((v.w - mean) * rstd * g.w);
        *(half4*)(xo + t * 4) = o;
    } else {
        int idx = blockIdx.x - ROWS;       // 0..4095
        int bx = idx & 127, by = idx >> 7; // 128 x 32
        const float* W; _Float16* WT; int N, n0;
        if (bx < 96) { W = Wq; WT = WqT; N = QKVW; n0 = bx * 32; }
        else         { W = Wo; WT = WoT; N = DIMX; n0 = (bx - 96) * 32; }
        int k0 = by * 32;
        int tx = t & 31, ty = t >> 5;      // 32 x 8
        #pragma unroll
        for (int i = 0; i < 32; i += 8)
            tile[ty + i][tx] = W[(size_t)(k0 + ty + i) * N + n0 + tx];
        __syncthreads();
        #pragma unroll
        for (int i = 0; i < 32; i += 8)
            WT[(size_t)(n0 + ty + i) * 1024 + k0 + tx] = (_Float16)tile[tx][ty + i];
    }
}

// ---------------------------------------------------------------------------
// Kernel 2a: deep-pipelined QKV GEMM, 96 KB LDS, NOW with m201-style
// fine-grained phase interleave (the m196 lever):
//   each K-tile = TWO barrier-paired phases at 16 MFMA/phase (~8 MFMA/barrier):
//     P1: {ds_read af0-3+bf0-3 || stage A(t+2)} BAR {lgkm0+schedbar, setprio,
//          16 MFMA (mf0-3 x nf0-3)} BAR
//     P2: {ds_read af4-7       || stage B(t+2)} BAR {lgkm0+schedbar, setprio,
//          16 MFMA (mf4-7 x nf0-3)} vmcnt(4) BAR
//   Ledger identical to R6 (proven): enter tile T with (T+1)'s 4 loads
//   outstanding; stage (T+2)'s 4 during T; vmcnt(4) at P2-end lands (T+1).
//   Tail: tile 30 vmcnt(0), tile 31 no wait. Buffers rotate t%3 (3 x 32KB).
//   Swizzle/staging/epilogue byte-identical to R6 (incl. the V-store fix).
// ---------------------------------------------------------------------------
__global__ __launch_bounds__(512, 2) void hgemm_qkv_big(const _Float16* __restrict__ A,
                                                        const _Float16* __restrict__ BT,
                                                        const float* __restrict__ qg,
                                                        const float* __restrict__ kg,
                                                        _Float16* __restrict__ qf,
                                                        _Float16* __restrict__ kf,
                                                        _Float16* __restrict__ vt) {
    extern __shared__ char smem[];               // 98304 B = 3 x 32768
    _Float16* smemh = (_Float16*)smem;
    const int K = DIMX;

    int t = threadIdx.x;
    int wave = t >> 6, lane = t & 63;
    int quad = lane >> 4, l16 = lane & 15;
    int mw = wave >> 2;                          // 0..1  (token group, 128 each)
    int nw = wave & 3;                           // 0..3  (feature group, 64 each)

    // XCD-chunked bijective swizzle of the 12 x 32 grid (384 = 8 * 48)
    int id  = blockIdx.y * 12 + blockIdx.x;
    int swz_id = (id & 7) * 48 + (id >> 3);
    int bx = swz_id % 12, by = swz_id / 12;
    size_t m0 = (size_t)by * 256, n0 = (size_t)bx * 256;

    floatx4 acc[8][4] = {};   // C^T frags: row=feature(nf,quad,r), col=token(mf,l16)

    // staging lane map: row = wave*32 + (l>>2) (+16 for 2nd GLD), chunk = l&3;
    // global k-chunk pre-swizzled with ((l>>3)&3) == (row>>1)&3
    int srow   = lane >> 2;
    int schunk = (lane & 3) ^ ((lane >> 3) & 3);
    const _Float16* agA = A  + (m0 + wave * 32 + srow) * (size_t)K + schunk * 8;
    const _Float16* bgB = BT + (n0 + wave * 32 + srow) * (size_t)K + schunk * 8;
    int rsw = (l16 >> 1) & 3;                    // read-side chunk swizzle

#define STAGE_A(TT, SB) do {                                                    \
        char* d_ = smem + (SB) * 32768 + wave * 2048;                           \
        const _Float16* g_ = agA + (size_t)(TT) * 32;                           \
        GLD_LDS16(g_, d_);                                                      \
        GLD_LDS16(g_ + 16 * (size_t)K, d_ + 1024);                              \
    } while (0)

#define STAGE_B(TT, SB) do {                                                    \
        char* d_ = smem + (SB) * 32768 + 16384 + wave * 2048;                   \
        const _Float16* g_ = bgB + (size_t)(TT) * 32;                           \
        GLD_LDS16(g_, d_);                                                      \
        GLD_LDS16(g_ + 16 * (size_t)K, d_ + 1024);                              \
    } while (0)

    // one K-tile = two barrier-paired phases (m201 cadence)
#define TILE(ST, RB, SB, DOST, WAIT_STMT) do {                                  \
        const _Float16* As_ = smemh + (RB) * 16384;                             \
        const _Float16* Bs_ = As_ + 8192;                                       \
        half8 a0[4], a1[4], bf[4];                                              \
        /* P1: reads + A-stage */                                               \
        _Pragma("unroll")                                                       \
        for (int i = 0; i < 4; i++)                                             \
            a0[i] = *(const half8*)&As_[(mw * 128 + i * 16 + l16) * 32          \
                                        + (quad ^ rsw) * 8];                    \
        _Pragma("unroll")                                                       \
        for (int nf = 0; nf < 4; nf++)                                          \
            bf[nf] = *(const half8*)&Bs_[(nw * 64 + nf * 16 + l16) * 32         \
                                         + (quad ^ rsw) * 8];                   \
        if (DOST) STAGE_A(ST, SB);                                              \
        __builtin_amdgcn_s_barrier();                                           \
        asm volatile("s_waitcnt lgkmcnt(0)" ::: "memory");                      \
        __builtin_amdgcn_sched_barrier(0);                                      \
        __builtin_amdgcn_s_setprio(1);                                          \
        _Pragma("unroll")                                                       \
        for (int i = 0; i < 4; i++)                                             \
            _Pragma("unroll")                                                   \
            for (int nf = 0; nf < 4; nf++)                                      \
                acc[i][nf] = __builtin_amdgcn_mfma_f32_16x16x32_f16(            \
                    bf[nf], a0[i], acc[i][nf], 0, 0, 0);                        \
        __builtin_amdgcn_s_setprio(0);                                          \
        __builtin_amdgcn_s_barrier();                                           \
        asm volatile("" ::: "memory");                                          \
        /* P2: reads + B-stage */                                               \
        _Pragma("unroll")                                                       \
        for (int i = 0; i < 4; i++)                                             \
            a1[i] = *(const half8*)&As_[(mw * 128 + (4 + i) * 16 + l16) * 32    \
                                        + (quad ^ rsw) * 8];                    \
        if (DOST) STAGE_B(ST, SB);                                              \
        __builtin_amdgcn_s_barrier();                                           \
        asm volatile("s_waitcnt lgkmcnt(0)" ::: "memory");                      \
        __builtin_amdgcn_sched_barrier(0);                                      \
        __builtin_amdgcn_s_setprio(1);                                          \
        _Pragma("unroll")                                                       \
        for (int i = 0; i < 4; i++)                                             \
            _Pragma("unroll")                                                   \
            for (int nf = 0; nf < 4; nf++)                                      \
                acc[4 + i][nf] = __builtin_amdgcn_mfma_f32_16x16x32_f16(        \
                    bf[nf], a1[i], acc[4 + i][nf], 0, 0, 0);                    \
        __builtin_amdgcn_s_setprio(0);                                          \
        WAIT_STMT;                                                              \
        __builtin_amdgcn_s_barrier();                                           \
        asm volatile("" ::: "memory");                                          \
    } while (0)

    // prologue: tiles 0 (buf0) and 1 (buf1) in flight; wait tile 0 (leave 4)
    STAGE_A(0, 0); STAGE_B(0, 0); STAGE_A(1, 1); STAGE_B(1, 1);
    asm volatile("s_waitcnt vmcnt(4)" ::: "memory");
    __builtin_amdgcn_s_barrier();
    asm volatile("" ::: "memory");

    for (int T = 0; T < 30; T += 3) {
        TILE(T + 2, 0, 2, 1, asm volatile("s_waitcnt vmcnt(4)" ::: "memory"));
        TILE(T + 3, 1, 0, 1, asm volatile("s_waitcnt vmcnt(4)" ::: "memory"));
        TILE(T + 4, 2, 1, 1, asm volatile("s_waitcnt vmcnt(4)" ::: "memory"));
    }
    TILE(0, 0, 0, 0, asm volatile("s_waitcnt vmcnt(0)" ::: "memory"));  // tile 30
    TILE(0, 1, 0, 0, ((void)0));                                        // tile 31

#undef TILE
#undef STAGE_A
#undef STAGE_B

    // epilogue: which = 0:q 1:k 2:v (block-uniform; n0 multiple of 256)
    int which = (int)(n0 >> 10);
    int nloc  = ((int)n0 & 1023) + nw * 64;      // feature offset within q/k/v
    int h = nloc >> 6;

    if (which < 2) {
        const float* g = (which == 0) ? qg : kg;
        float emul = (which == 0) ? LOG2E : 1.0f;
        _Float16* dstbuf = (which == 0) ? qf : kf;
        #pragma unroll
        for (int mf = 0; mf < 8; mf++) {
            size_t tok = m0 + mw * 128 + mf * 16 + l16;
            int b = (int)(tok >> 10), ntk = (int)(tok & 1023);
            _Float16* dst = dstbuf + (((size_t)(b * 16 + h)) * 1024 + ntk) * 64;
            float ss = 0.f;
            #pragma unroll
            for (int nf = 0; nf < 4; nf++)
                #pragma unroll
                for (int r = 0; r < 4; r++) ss += acc[mf][nf][r] * acc[mf][nf][r];
            ss += __shfl_xor(ss, 16);
            ss += __shfl_xor(ss, 32);
            float scale = 8.0f * emul / fmaxf(sqrtf(ss), 1e-12f);
            #pragma unroll
            for (int nf = 0; nf < 4; nf++) {
                half4 p;
                #pragma unroll
                for (int r = 0; r < 4; r++)
                    p[r] = (_Float16)(acc[mf][nf][r] * scale *
                                      g[h * 64 + nf * 16 + quad * 4 + r]);
                *(half4*)(dst + nf * 16 + quad * 4) = p;
            }
        }
    } else {
        // V: direct transposed store. vt[((bh*16+nt)*64 + d)*64 + (ntk&63)]
        // within-block token = (mf&3)*16 + l16 (nt already advances at mf=4)
        #pragma unroll
        for (int mf = 0; mf < 8; mf++) {
            size_t tok = m0 + mw * 128 + mf * 16 + l16;
            int b = (int)(tok >> 10), ntk = (int)(tok & 1023);
            int nt = ntk >> 6;
            _Float16* vd = vt + ((size_t)((b * 16 + h) * 16 + nt) * 64) * 64
                              + (mf & 3) * 16 + l16;
            #pragma unroll
            for (int nf = 0; nf < 4; nf++)
                #pragma unroll
                for (int r = 0; r < 4; r++)
                    vd[(size_t)(nf * 16 + quad * 4 + r) * 64] =
                        (_Float16)acc[mf][nf][r];
        }
    }
}

// ---------------------------------------------------------------------------
// Kernel 2b (fallback): proven baseline 128x128 QKV GEMM (static 32 KB LDS).
// ---------------------------------------------------------------------------
__global__ __launch_bounds__(256) void hgemm_qkv_small(const _Float16* __restrict__ A,
                                                       const _Float16* __restrict__ BT,
                                                       const float* __restrict__ qg,
                                                       const float* __restrict__ kg,
                                                       _Float16* __restrict__ qf,
                                                       _Float16* __restrict__ kf,
                                                       _Float16* __restrict__ vt) {
    __shared__ _Float16 As[128 * 64];
    __shared__ _Float16 Bs[128 * 64];
    const int K = DIMX;

    int t = threadIdx.x;
    int wave = t >> 6, lane = t & 63;
    int quad = lane >> 4, l16 = lane & 15;
    int wm = (wave >> 1) * 64;
    int wn = (wave & 1) * 64;
    size_t m0 = (size_t)blockIdx.y * 128, n0 = (size_t)blockIdx.x * 128;

    floatx4 acc[4][4] = {};

    int sr = t >> 3, sg = t & 7;
    int swz = sg ^ (sr & 7);
    const _Float16* ag = A  + (m0 + sr) * (size_t)K + swz * 8;
    const _Float16* bg = BT + (n0 + sr) * (size_t)K + swz * 8;
    char* lA = (char*)As + wave * 1024;
    char* lB = (char*)Bs + wave * 1024;

    for (int k0 = 0; k0 < K; k0 += 64) {
        #pragma unroll
        for (int i = 0; i < 4; i++) {
            GLD_LDS16(ag + (size_t)(i * 32) * K + k0, lA + i * 4096);
            GLD_LDS16(bg + (size_t)(i * 32) * K + k0, lB + i * 4096);
        }
        __syncthreads();

        half8 af[2][4], bf[2][4];
        #pragma unroll
        for (int kk = 0; kk < 2; kk++) {
            #pragma unroll
            for (int mf = 0; mf < 4; mf++)
                af[kk][mf] = *(const half8*)&As[(wm + mf * 16 + l16) * 64
                                 + (((kk * 4 + quad) ^ (l16 & 7)) * 8)];
            #pragma unroll
            for (int nf = 0; nf < 4; nf++)
                bf[kk][nf] = *(const half8*)&Bs[(wn + nf * 16 + l16) * 64
                                 + (((kk * 4 + quad) ^ (l16 & 7)) * 8)];
        }

        #pragma unroll
        for (int kk = 0; kk < 2; kk++)
            #pragma unroll
            for (int mf = 0; mf < 4; mf++)
                #pragma unroll
                for (int nf = 0; nf < 4; nf++)
                    acc[mf][nf] = __builtin_amdgcn_mfma_f32_16x16x32_f16(
                        bf[kk][nf], af[kk][mf], acc[mf][nf], 0, 0, 0);
        __syncthreads();
    }

    int which = (int)(n0 >> 10);
    int nloc  = ((int)n0 & 1023) + wn;
    int h = nloc >> 6;

    if (which < 2) {
        const float* g = (which == 0) ? qg : kg;
        float emul = (which == 0) ? LOG2E : 1.0f;
        _Float16* dstbuf = (which == 0) ? qf : kf;
        #pragma unroll
        for (int mf = 0; mf < 4; mf++) {
            size_t tok = m0 + wm + mf * 16 + l16;
            int b = (int)(tok >> 10), ntk = (int)(tok & 1023);
            _Float16* dst = dstbuf + (((size_t)(b * 16 + h)) * 1024 + ntk) * 64;
            float ss = 0.f;
            #pragma unroll
            for (int nf = 0; nf < 4; nf++)
                #pragma unroll
                for (int r = 0; r < 4; r++) ss += acc[mf][nf][r] * acc[mf][nf][r];
            ss += __shfl_xor(ss, 16);
            ss += __shfl_xor(ss, 32);
            float scale = 8.0f * emul / fmaxf(sqrtf(ss), 1e-12f);
            #pragma unroll
            for (int nf = 0; nf < 4; nf++) {
                half4 p;
                #pragma unroll
                for (int r = 0; r < 4; r++)
                    p[r] = (_Float16)(acc[mf][nf][r] * scale *
                                      g[h * 64 + nf * 16 + quad * 4 + r]);
                *(half4*)(dst + nf * 16 + quad * 4) = p;
            }
        }
    } else {
        #pragma unroll
        for (int mf = 0; mf < 4; mf++) {
            size_t tok = m0 + wm + mf * 16 + l16;
            int b = (int)(tok >> 10), ntk = (int)(tok & 1023);
            int nt = ntk >> 6;
            _Float16* vd = vt + ((size_t)((b * 16 + h) * 16 + nt) * 64) * 64
                              + mf * 16 + l16;
            #pragma unroll
            for (int nf = 0; nf < 4; nf++)
                #pragma unroll
                for (int r = 0; r < 4; r++)
                    vd[(size_t)(nf * 16 + quad * 4 + r) * 64] =
                        (_Float16)acc[mf][nf][r];
        }
    }
}

// ---------------------------------------------------------------------------
// Kernel 3: flash attention (unchanged)
// ---------------------------------------------------------------------------
__global__ __launch_bounds__(256, 3) void flash_kernel(const _Float16* __restrict__ qf,
                                                       const _Float16* __restrict__ kf,
                                                       const _Float16* __restrict__ vt,
                                                       _Float16* __restrict__ obuf) {
    __shared__ _Float16 Ks[2][64 * 64];
    __shared__ _Float16 VTs[2][64 * 64];
    __shared__ _Float16 Ps[4][16][68];

    int t = threadIdx.x;
    int wave = t >> 6, lane = t & 63;
    int quad = lane >> 4, l16 = lane & 15;
    int bh = blockIdx.x & 127, qt = blockIdx.x >> 7;

    const _Float16* qb = qf + ((size_t)bh * 1024 + qt * 128) * 64;
    const _Float16* kb = kf + (size_t)bh * 65536;
    const _Float16* vb = vt + (size_t)bh * 65536;

    half8 aq[2][2];
    #pragma unroll
    for (int st = 0; st < 2; st++) {
        const _Float16* qrow = qb + (wave * 32 + st * 16 + l16) * 64;
        aq[st][0] = *(const half8*)(qrow + quad * 8);
        aq[st][1] = *(const half8*)(qrow + 32 + quad * 8);
    }

    floatx4 o[2][4] = {};
    float m_i[2] = {-INFINITY, -INFINITY};
    float l_i[2] = {0.f, 0.f};

    int sr = t >> 3;
    int sg = t & 7;
    int swz = sg ^ (sr & 7);

    #pragma unroll
    for (int i = 0; i < 2; i++) {
        GLD_LDS16(kb + (i * 32 + sr) * 64 + swz * 8, (char*)Ks[0]  + wave * 1024 + i * 4096);
        GLD_LDS16(vb + (i * 32 + sr) * 64 + swz * 8, (char*)VTs[0] + wave * 1024 + i * 4096);
    }

    for (int kt = 0; kt < 16; kt++) {
        int cur = kt & 1;
        __syncthreads();

        if (kt < 15) {
            const _Float16* kn = kb + (size_t)(kt + 1) * 4096;
            const _Float16* vn = vb + (size_t)(kt + 1) * 4096;
            #pragma unroll
            for (int i = 0; i < 2; i++) {
                GLD_LDS16(kn + (i * 32 + sr) * 64 + swz * 8,
                          (char*)Ks[cur ^ 1]  + wave * 1024 + i * 4096);
                GLD_LDS16(vn + (i * 32 + sr) * 64 + swz * 8,
                          (char*)VTs[cur ^ 1] + wave * 1024 + i * 4096);
            }
        }

        #pragma unroll
        for (int st = 0; st < 2; st++) {
            floatx4 sc[4] = {};
            #pragma unroll
            for (int kc = 0; kc < 2; kc++) {
                #pragma unroll
                for (int nf = 0; nf < 4; nf++) {
                    half8 ak = *(const half8*)&Ks[cur][(nf * 16 + l16) * 64
                                    + (((kc * 4 + quad) ^ (l16 & 7)) * 8)];
                    sc[nf] = __builtin_amdgcn_mfma_f32_16x16x32_f16(
                        ak, aq[st][kc], sc[nf], 0, 0, 0);
                }
            }

            float mx = sc[0][0];
            #pragma unroll
            for (int nf = 0; nf < 4; nf++)
                #pragma unroll
                for (int r = 0; r < 4; r++) mx = fmaxf(mx, sc[nf][r]);
            mx = fmaxf(mx, __shfl_xor(mx, 16));
            mx = fmaxf(mx, __shfl_xor(mx, 32));
            if (mx > m_i[st]) {
                float alpha = fexp2(m_i[st] - mx);
                l_i[st] *= alpha;
                #pragma unroll
                for (int nf = 0; nf < 4; nf++) o[st][nf] *= alpha;
                m_i[st] = mx;
            }
            float mcur = m_i[st];
            float psum = 0.f;
            #pragma unroll
            for (int nf = 0; nf < 4; nf++)
                #pragma unroll
                for (int r = 0; r < 4; r++) {
                    float p = fexp2(sc[nf][r] - mcur);
                    sc[nf][r] = p;
                    psum += p;
                }
            l_i[st] += psum;

            #pragma unroll
            for (int nf = 0; nf < 4; nf++) {
                half4 p4;
                #pragma unroll
                for (int r = 0; r < 4; r++) p4[r] = (_Float16)sc[nf][r];
                *(half4*)&Ps[wave][l16][nf * 16 + quad * 4] = p4;
            }

            #pragma unroll
            for (int kc = 0; kc < 2; kc++) {
                half4 p0 = *(const half4*)&Ps[wave][l16][kc * 32 + quad * 8];
                half4 p1 = *(const half4*)&Ps[wave][l16][kc * 32 + quad * 8 + 4];
                half8 bp;
                #pragma unroll
                for (int j = 0; j < 4; j++) { bp[j] = p0[j]; bp[4 + j] = p1[j]; }
                #pragma unroll
                for (int nf = 0; nf < 4; nf++) {
                    half8 av = *(const half8*)&VTs[cur][(nf * 16 + l16) * 64
                                    + (((kc * 4 + quad) ^ (l16 & 7)) * 8)];
                    o[st][nf] = __builtin_amdgcn_mfma_f32_16x16x32_f16(
                        av, bp, o[st][nf], 0, 0, 0);
                }
            }
        }
    }

    int b = bh >> 4, h = bh & 15;
    #pragma unroll
    for (int st = 0; st < 2; st++) {
        float lsum = l_i[st];
        lsum += __shfl_xor(lsum, 16);
        lsum += __shfl_xor(lsum, 32);
        float inv = 1.0f / lsum;
        size_t row = (size_t)b * NSEQ + qt * 128 + wave * 32 + st * 16 + l16;
        #pragma unroll
        for (int nf = 0; nf < 4; nf++) {
            half4 o4;
            #pragma unroll
            for (int r = 0; r < 4; r++) o4[r] = (_Float16)(o[st][nf][r] * inv);
            *(half4*)(obuf + row * 1024 + h * 64 + nf * 16 + quad * 4) = o4;
        }
    }
}

// ---------------------------------------------------------------------------
// Kernel 4: out-projection GEMM (unchanged)
// ---------------------------------------------------------------------------
__global__ __launch_bounds__(256) void hgemm_out(const _Float16* __restrict__ A,
                                                 const _Float16* __restrict__ BT,
                                                 float* __restrict__ C) {
    __shared__ _Float16 As[128 * 64];
    __shared__ _Float16 Bs[128 * 64];
    const int K = DIMX, N = DIMX;

    int t = threadIdx.x;
    int wave = t >> 6, lane = t & 63;
    int quad = lane >> 4, l16 = lane & 15;
    int wm = (wave >> 1) * 64, wn = (wave & 1) * 64;
    size_t m0 = (size_t)blockIdx.y * 128, n0 = (size_t)blockIdx.x * 128;

    floatx4 acc[4][4] = {};

    int sr = t >> 3, sg = t & 7;
    int swz = sg ^ (sr & 7);
    const _Float16* ag = A  + (m0 + sr) * (size_t)K + swz * 8;
    const _Float16* bg = BT + (n0 + sr) * (size_t)K + swz * 8;
    char* lA = (char*)As + wave * 1024;
    char* lB = (char*)Bs + wave * 1024;

    for (int k0 = 0; k0 < K; k0 += 64) {
        #pragma unroll
        for (int i = 0; i < 4; i++) {
            GLD_LDS16(ag + (size_t)(i * 32) * K + k0, lA + i * 4096);
            GLD_LDS16(bg + (size_t)(i * 32) * K + k0, lB + i * 4096);
        }
        __syncthreads();

        half8 af[2][4], bf[2][4];
        #pragma unroll
        for (int kk = 0; kk < 2; kk++) {
            #pragma unroll
            for (int mf = 0; mf < 4; mf++)
                af[kk][mf] = *(const half8*)&As[(wm + mf * 16 + l16) * 64
                                 + (((kk * 4 + quad) ^ (l16 & 7)) * 8)];
            #pragma unroll
            for (int nf = 0; nf < 4; nf++)
                bf[kk][nf] = *(const half8*)&Bs[(wn + nf * 16 + l16) * 64
                                 + (((kk * 4 + quad) ^ (l16 & 7)) * 8)];
        }

        #pragma unroll
        for (int kk = 0; kk < 2; kk++)
            #pragma unroll
            for (int mf = 0; mf < 4; mf++)
                #pragma unroll
                for (int nf = 0; nf < 4; nf++)
                    acc[mf][nf] = __builtin_amdgcn_mfma_f32_16x16x32_f16(
                        bf[kk][nf], af[kk][mf], acc[mf][nf], 0, 0, 0);
        __syncthreads();
    }

    #pragma unroll
    for (int mf = 0; mf < 4; mf++) {
        size_t tok = m0 + wm + mf * 16 + l16;
        #pragma unroll
        for (int nf = 0; nf < 4; nf++)
            *(floatx4*)(C + tok * N + n0 + wn + nf * 16 + quad * 4) = acc[mf][nf];
    }
}

// ---------------------------------------------------------------------------
extern "C" void kernel_launch(void* const* d_in, const int* in_sizes, int n_in,
                              void* d_out, int out_size, void* d_ws, size_t ws_size,
                              hipStream_t stream) {
    const float* x     = (const float*)d_in[0];
    const float* ln_g  = (const float*)d_in[1];
    const float* q_g   = (const float*)d_in[2];
    const float* k_g   = (const float*)d_in[3];
    const float* w_qkv = (const float*)d_in[4];
    const float* w_out = (const float*)d_in[5];
    float* out = (float*)d_out;

    char* base = (char*)d_ws;
    _Float16* xn    = (_Float16*)(base);
    _Float16* wqkvT = (_Float16*)(base + (16ull << 20));
    _Float16* woutT = (_Float16*)(base + (22ull << 20));
    _Float16* qf    = (_Float16*)(base + (24ull << 20));
    _Float16* kf    = (_Float16*)(base + (40ull << 20));
    _Float16* vt    = (_Float16*)(base + (56ull << 20));
    _Float16* obuf  = (_Float16*)(base + (72ull << 20));

    // Probe once: 96 KB dynamic LDS opt-in (proven launchable).
    static int use_big = -1;
    if (use_big < 0) {
        int ok = 0;
        if (hipFuncSetAttribute((const void*)hgemm_qkv_big,
                                hipFuncAttributeMaxDynamicSharedMemorySize,
                                98304) == hipSuccess) {
            hipFuncAttributes fa;
            if (hipFuncGetAttributes(&fa, (const void*)hgemm_qkv_big) == hipSuccess
                && fa.maxDynamicSharedSizeBytes >= 98304)
                ok = 1;
        }
        use_big = ok;
    }

    lnw_kernel<<<ROWS + 4096, 256, 0, stream>>>(x, ln_g, w_qkv, w_out,
                                                xn, wqkvT, woutT);

    if (use_big) {
        dim3 g1(QKVW / 256, ROWS / 256);   // 12 x 32 = 384 blocks
        hgemm_qkv_big<<<g1, 512, 98304, stream>>>(xn, wqkvT, q_g, k_g, qf, kf, vt);
    } else {
        dim3 g1(QKVW / 128, ROWS / 128);   // 24 x 64 = 1536 blocks
        hgemm_qkv_small<<<g1, 256, 0, stream>>>(xn, wqkvT, q_g, k_g, qf, kf, vt);
    }

    flash_kernel<<<NB * HEADS * (NSEQ / 128), 256, 0, stream>>>(qf, kf, vt, obuf);

    dim3 g2(DIMX / 128, ROWS / 128);
    hgemm_out<<<g2, 256, 0, stream>>>(obuf, woutT, out);
}

// Round 9
// 248.642 us; speedup vs baseline: 1.0629x; 1.0629x over previous
//
#include <hip/hip_runtime.h>
#include <hip/hip_bf16.h>
#include <math.h>

#define DIMX   1024
#define HEADS  16
#define DH     64
#define NB     8
#define NSEQ   1024
#define ROWS   (NB * NSEQ)        // 8192
#define QKVW   (3 * DIMX)         // 3072
#define LOG2E  1.44269504088896f

typedef _Float16 half8 __attribute__((ext_vector_type(8)));
typedef _Float16 half4 __attribute__((ext_vector_type(4)));
typedef float floatx4 __attribute__((ext_vector_type(4)));

// async global->LDS, 16B per lane. lptr must be wave-uniform; HW adds lane*16.
#define GLD_LDS16(gptr, lptr) __builtin_amdgcn_global_load_lds( \
    (const __attribute__((address_space(1))) void*)(gptr),      \
    (__attribute__((address_space(3))) void*)(lptr), 16, 0, 0)

__device__ __forceinline__ float fexp2(float x) {
#if __has_builtin(__builtin_amdgcn_exp2f)
    return __builtin_amdgcn_exp2f(x);
#else
    return __expf(x * 0.69314718056f);
#endif
}

// ---------------------------------------------------------------------------
// Kernel 1: merged LayerNorm (blocks 0..8191) + weight transpose (8192..12287)
// ---------------------------------------------------------------------------
__global__ __launch_bounds__(256) void lnw_kernel(const float* __restrict__ x,
                                                  const float* __restrict__ gamma,
                                                  const float* __restrict__ Wq,
                                                  const float* __restrict__ Wo,
                                                  _Float16* __restrict__ xn,
                                                  _Float16* __restrict__ WqT,
                                                  _Float16* __restrict__ WoT) {
    __shared__ float tile[32][33];
    __shared__ float sbuf[4], ssbuf[4];
    int t = threadIdx.x;

    if (blockIdx.x < ROWS) {
        int row = blockIdx.x;
        const float* xr = x + (size_t)row * DIMX;
        _Float16* xo = xn + (size_t)row * DIMX;

        float4 v = ((const float4*)xr)[t];
        float s  = v.x + v.y + v.z + v.w;
        float ss = v.x*v.x + v.y*v.y + v.z*v.z + v.w*v.w;
        #pragma unroll
        for (int o = 32; o > 0; o >>= 1) {
            s  += __shfl_down(s, o);
            ss += __shfl_down(ss, o);
        }
        int lane = t & 63, wid = t >> 6;
        if (lane == 0) { sbuf[wid] = s; ssbuf[wid] = ss; }
        __syncthreads();
        if (t == 0) {
            float a = 0.f, b2 = 0.f;
            for (int i = 0; i < 4; i++) { a += sbuf[i]; b2 += ssbuf[i]; }
            sbuf[0] = a; ssbuf[0] = b2;
        }
        __syncthreads();
        float mean = sbuf[0] * (1.0f / DIMX);
        float var  = ssbuf[0] * (1.0f / DIMX) - mean * mean;
        float rstd = rsqrtf(var + 1e-5f);

        float4 g = ((const float4*)gamma)[t];
        half4 o;
        o.x = (_Float16)((v.x - mean) * rstd * g.x);
        o.y = (_Float16)((v.y - mean) * rstd * g.y);
        o.z = (_Float16)((v.z - mean) * rstd * g.z);
        o.w = (_Float16)((v.w - mean) * rstd * g.w);
        *(half4*)(xo + t * 4) = o;
    } else {
        int idx = blockIdx.x - ROWS;       // 0..4095
        int bx = idx & 127, by = idx >> 7; // 128 x 32
        const float* W; _Float16* WT; int N, n0;
        if (bx < 96) { W = Wq; WT = WqT; N = QKVW; n0 = bx * 32; }
        else         { W = Wo; WT = WoT; N = DIMX; n0 = (bx - 96) * 32; }
        int k0 = by * 32;
        int tx = t & 31, ty = t >> 5;      // 32 x 8
        #pragma unroll
        for (int i = 0; i < 32; i += 8)
            tile[ty + i][tx] = W[(size_t)(k0 + ty + i) * N + n0 + tx];
        __syncthreads();
        #pragma unroll
        for (int i = 0; i < 32; i += 8)
            WT[(size_t)(n0 + ty + i) * 1024 + k0 + tx] = (_Float16)tile[tx][ty + i];
    }
}

// ---------------------------------------------------------------------------
// Kernel 2: fused QKV GEMM + RMS(q,k) + per-head repack + V-transpose-store.
// R0-proven structure (128x128 tile, 256 thr, 3 blocks/CU cross-block overlap)
// + XCD-chunked bijective block swizzle (1536 = 8 x 192). Each XCD owns
// 8 contiguous M-panels x all 24 N-tiles, N-fastest: one 0.5 MB A-panel hot
// per XCD, per-XCD A footprint 4 MB = its L2.
// ---------------------------------------------------------------------------
__global__ __launch_bounds__(256) void hgemm_qkv(const _Float16* __restrict__ A,
                                                 const _Float16* __restrict__ BT,
                                                 const float* __restrict__ qg,
                                                 const float* __restrict__ kg,
                                                 _Float16* __restrict__ qf,
                                                 _Float16* __restrict__ kf,
                                                 _Float16* __restrict__ vt) {
    __shared__ _Float16 As[128 * 64];
    __shared__ _Float16 Bs[128 * 64];
    const int K = DIMX;

    int t = threadIdx.x;
    int wave = t >> 6, lane = t & 63;
    int quad = lane >> 4, l16 = lane & 15;
    int wm = (wave >> 1) * 64;           // token offset within tile
    int wn = (wave & 1) * 64;            // feature offset within tile

    // XCD-chunked bijective swizzle: 1536 blocks = 8 XCDs x 192
    // (8 M-panels x 24 N-tiles each, N-fastest within the chunk)
    int p  = (int)(blockIdx.y * 24 + blockIdx.x);
    int sw = (p & 7) * 192 + (p >> 3);
    size_t m0 = (size_t)(sw / 24) * 128, n0 = (size_t)(sw % 24) * 128;

    floatx4 acc[4][4] = {};   // C^T frags: row=feature(nf,quad,r), col=token(mf,l16)

    int sr = t >> 3, sg = t & 7;
    int swz = sg ^ (sr & 7);
    const _Float16* ag = A  + (m0 + sr) * (size_t)K + swz * 8;
    const _Float16* bg = BT + (n0 + sr) * (size_t)K + swz * 8;
    char* lA = (char*)As + wave * 1024;
    char* lB = (char*)Bs + wave * 1024;

    for (int k0 = 0; k0 < K; k0 += 64) {
        #pragma unroll
        for (int i = 0; i < 4; i++) {
            GLD_LDS16(ag + (size_t)(i * 32) * K + k0, lA + i * 4096);
            GLD_LDS16(bg + (size_t)(i * 32) * K + k0, lB + i * 4096);
        }
        __syncthreads();

        half8 af[2][4], bf[2][4];
        #pragma unroll
        for (int kk = 0; kk < 2; kk++) {
            #pragma unroll
            for (int mf = 0; mf < 4; mf++)
                af[kk][mf] = *(const half8*)&As[(wm + mf * 16 + l16) * 64
                                 + (((kk * 4 + quad) ^ (l16 & 7)) * 8)];
            #pragma unroll
            for (int nf = 0; nf < 4; nf++)
                bf[kk][nf] = *(const half8*)&Bs[(wn + nf * 16 + l16) * 64
                                 + (((kk * 4 + quad) ^ (l16 & 7)) * 8)];
        }

        #pragma unroll
        for (int kk = 0; kk < 2; kk++)
            #pragma unroll
            for (int mf = 0; mf < 4; mf++)
                #pragma unroll
                for (int nf = 0; nf < 4; nf++)
                    acc[mf][nf] = __builtin_amdgcn_mfma_f32_16x16x32_f16(
                        bf[kk][nf], af[kk][mf], acc[mf][nf], 0, 0, 0);
        __syncthreads();
    }

    // epilogue: which = 0:q 1:k 2:v (block-uniform)
    int which = (int)(n0 >> 10);
    int nloc  = ((int)n0 & 1023) + wn;   // feature offset within q/k/v
    int h = nloc >> 6;

    if (which < 2) {
        const float* g = (which == 0) ? qg : kg;
        float emul = (which == 0) ? LOG2E : 1.0f;
        _Float16* dstbuf = (which == 0) ? qf : kf;
        #pragma unroll
        for (int mf = 0; mf < 4; mf++) {
            size_t tok = m0 + wm + mf * 16 + l16;
            int b = (int)(tok >> 10), ntk = (int)(tok & 1023);
            _Float16* dst = dstbuf + (((size_t)(b * 16 + h)) * 1024 + ntk) * 64;
            float ss = 0.f;
            #pragma unroll
            for (int nf = 0; nf < 4; nf++)
                #pragma unroll
                for (int r = 0; r < 4; r++) ss += acc[mf][nf][r] * acc[mf][nf][r];
            ss += __shfl_xor(ss, 16);
            ss += __shfl_xor(ss, 32);
            float scale = 8.0f * emul / fmaxf(sqrtf(ss), 1e-12f);
            #pragma unroll
            for (int nf = 0; nf < 4; nf++) {
                half4 ph;
                #pragma unroll
                for (int r = 0; r < 4; r++)
                    ph[r] = (_Float16)(acc[mf][nf][r] * scale *
                                       g[h * 64 + nf * 16 + quad * 4 + r]);
                *(half4*)(dst + nf * 16 + quad * 4) = ph;
            }
        }
    } else {
        // V: direct transposed store. vt[((bh*16+nt)*64 + d)*64 + tl]
        // lane value acc[mf][nf][r]: d = nf*16+quad*4+r, tl = mf*16+l16 (mf<4).
        #pragma unroll
        for (int mf = 0; mf < 4; mf++) {
            size_t tok = m0 + wm + mf * 16 + l16;
            int b = (int)(tok >> 10), ntk = (int)(tok & 1023);
            int nt = ntk >> 6;
            _Float16* vd = vt + ((size_t)((b * 16 + h) * 16 + nt) * 64) * 64
                              + mf * 16 + l16;
            #pragma unroll
            for (int nf = 0; nf < 4; nf++)
                #pragma unroll
                for (int r = 0; r < 4; r++)
                    vd[(size_t)(nf * 16 + quad * 4 + r) * 64] =
                        (_Float16)acc[mf][nf][r];
        }
    }
}

// ---------------------------------------------------------------------------
// Kernel 3: flash attention, transposed dataflow, exp2 softmax, double-
// buffered K/V staging. bh-major block mapping already XCD-optimal
// (all 8 q-tiles of a bh land on XCD bh%8; 4 MB K/V per XCD). Unchanged.
// ---------------------------------------------------------------------------
__global__ __launch_bounds__(256, 3) void flash_kernel(const _Float16* __restrict__ qf,
                                                       const _Float16* __restrict__ kf,
                                                       const _Float16* __restrict__ vt,
                                                       _Float16* __restrict__ obuf) {
    __shared__ _Float16 Ks[2][64 * 64];    // [buf][kcol][dh], group-swizzled
    __shared__ _Float16 VTs[2][64 * 64];   // [buf][dh][kcol], group-swizzled
    __shared__ _Float16 Ps[4][16][68];     // per-wave P^T [qrow][kcol]

    int t = threadIdx.x;
    int wave = t >> 6, lane = t & 63;
    int quad = lane >> 4, l16 = lane & 15;
    int bh = blockIdx.x & 127, qt = blockIdx.x >> 7;

    const _Float16* qb = qf + ((size_t)bh * 1024 + qt * 128) * 64;
    const _Float16* kb = kf + (size_t)bh * 65536;
    const _Float16* vb = vt + (size_t)bh * 65536;

    half8 aq[2][2];
    #pragma unroll
    for (int st = 0; st < 2; st++) {
        const _Float16* qrow = qb + (wave * 32 + st * 16 + l16) * 64;
        aq[st][0] = *(const half8*)(qrow + quad * 8);
        aq[st][1] = *(const half8*)(qrow + 32 + quad * 8);
    }

    floatx4 o[2][4] = {};
    float m_i[2] = {-INFINITY, -INFINITY};
    float l_i[2] = {0.f, 0.f};

    int sr = t >> 3;
    int sg = t & 7;
    int swz = sg ^ (sr & 7);

    // prologue: tile 0 -> buffer 0
    #pragma unroll
    for (int i = 0; i < 2; i++) {
        GLD_LDS16(kb + (i * 32 + sr) * 64 + swz * 8, (char*)Ks[0]  + wave * 1024 + i * 4096);
        GLD_LDS16(vb + (i * 32 + sr) * 64 + swz * 8, (char*)VTs[0] + wave * 1024 + i * 4096);
    }

    for (int kt = 0; kt < 16; kt++) {
        int cur = kt & 1;
        __syncthreads();   // drains cur's DMA (in flight for a full compute phase)

        if (kt < 15) {
            const _Float16* kn = kb + (size_t)(kt + 1) * 4096;
            const _Float16* vn = vb + (size_t)(kt + 1) * 4096;
            #pragma unroll
            for (int i = 0; i < 2; i++) {
                GLD_LDS16(kn + (i * 32 + sr) * 64 + swz * 8,
                          (char*)Ks[cur ^ 1]  + wave * 1024 + i * 4096);
                GLD_LDS16(vn + (i * 32 + sr) * 64 + swz * 8,
                          (char*)VTs[cur ^ 1] + wave * 1024 + i * 4096);
            }
        }

        #pragma unroll
        for (int st = 0; st < 2; st++) {
            // S^T = K Q^T (log2-domain scores; qf pre-scaled by LOG2E)
            floatx4 sc[4] = {};
            #pragma unroll
            for (int kc = 0; kc < 2; kc++) {
                #pragma unroll
                for (int nf = 0; nf < 4; nf++) {
                    half8 ak = *(const half8*)&Ks[cur][(nf * 16 + l16) * 64
                                    + (((kc * 4 + quad) ^ (l16 & 7)) * 8)];
                    sc[nf] = __builtin_amdgcn_mfma_f32_16x16x32_f16(
                        ak, aq[st][kc], sc[nf], 0, 0, 0);
                }
            }

            // online softmax (base-2): lane owns one q-row
            float mx = sc[0][0];
            #pragma unroll
            for (int nf = 0; nf < 4; nf++)
                #pragma unroll
                for (int r = 0; r < 4; r++) mx = fmaxf(mx, sc[nf][r]);
            mx = fmaxf(mx, __shfl_xor(mx, 16));
            mx = fmaxf(mx, __shfl_xor(mx, 32));
            if (mx > m_i[st]) {
                float alpha = fexp2(m_i[st] - mx);
                l_i[st] *= alpha;
                #pragma unroll
                for (int nf = 0; nf < 4; nf++) o[st][nf] *= alpha;
                m_i[st] = mx;
            }
            float mcur = m_i[st];
            float psum = 0.f;
            #pragma unroll
            for (int nf = 0; nf < 4; nf++)
                #pragma unroll
                for (int r = 0; r < 4; r++) {
                    float p = fexp2(sc[nf][r] - mcur);
                    sc[nf][r] = p;
                    psum += p;
                }
            l_i[st] += psum;

            // P^T -> LDS (b64 writes; stride 68 elems = conflict-free)
            #pragma unroll
            for (int nf = 0; nf < 4; nf++) {
                half4 p4;
                #pragma unroll
                for (int r = 0; r < 4; r++) p4[r] = (_Float16)sc[nf][r];
                *(half4*)&Ps[wave][l16][nf * 16 + quad * 4] = p4;
            }

            // O^T += V^T P^T
            #pragma unroll
            for (int kc = 0; kc < 2; kc++) {
                half4 p0 = *(const half4*)&Ps[wave][l16][kc * 32 + quad * 8];
                half4 p1 = *(const half4*)&Ps[wave][l16][kc * 32 + quad * 8 + 4];
                half8 bp;
                #pragma unroll
                for (int j = 0; j < 4; j++) { bp[j] = p0[j]; bp[4 + j] = p1[j]; }
                #pragma unroll
                for (int nf = 0; nf < 4; nf++) {
                    half8 av = *(const half8*)&VTs[cur][(nf * 16 + l16) * 64
                                    + (((kc * 4 + quad) ^ (l16 & 7)) * 8)];
                    o[st][nf] = __builtin_amdgcn_mfma_f32_16x16x32_f16(
                        av, bp, o[st][nf], 0, 0, 0);
                }
            }
        }
    }

    int b = bh >> 4, h = bh & 15;
    #pragma unroll
    for (int st = 0; st < 2; st++) {
        float lsum = l_i[st];
        lsum += __shfl_xor(lsum, 16);
        lsum += __shfl_xor(lsum, 32);
        float inv = 1.0f / lsum;
        size_t row = (size_t)b * NSEQ + qt * 128 + wave * 32 + st * 16 + l16;
        #pragma unroll
        for (int nf = 0; nf < 4; nf++) {
            half4 o4;
            #pragma unroll
            for (int r = 0; r < 4; r++) o4[r] = (_Float16)(o[st][nf][r] * inv);
            *(half4*)(obuf + row * 1024 + h * 64 + nf * 16 + quad * 4) = o4;
        }
    }
}

// ---------------------------------------------------------------------------
// Kernel 4: out-projection GEMM, fp32 out, swapped epilogue -> float4 stores.
// + XCD-chunked bijective swizzle (512 = 8 x 64; per-XCD obuf panels
// 2 MB + woutT 2 MB = 4 MB = per-XCD L2).
// ---------------------------------------------------------------------------
__global__ __launch_bounds__(256) void hgemm_out(const _Float16* __restrict__ A,
                                                 const _Float16* __restrict__ BT,
                                                 float* __restrict__ C) {
    __shared__ _Float16 As[128 * 64];
    __shared__ _Float16 Bs[128 * 64];
    const int K = DIMX, N = DIMX;

    int t = threadIdx.x;
    int wave = t >> 6, lane = t & 63;
    int quad = lane >> 4, l16 = lane & 15;
    int wm = (wave >> 1) * 64, wn = (wave & 1) * 64;

    // XCD-chunked bijective swizzle: 512 blocks = 8 XCDs x 64
    int p  = (int)(blockIdx.y * 8 + blockIdx.x);
    int sw = (p & 7) * 64 + (p >> 3);
    size_t m0 = (size_t)(sw >> 3) * 128, n0 = (size_t)(sw & 7) * 128;

    floatx4 acc[4][4] = {};

    int sr = t >> 3, sg = t & 7;
    int swz = sg ^ (sr & 7);
    const _Float16* ag = A  + (m0 + sr) * (size_t)K + swz * 8;
    const _Float16* bg = BT + (n0 + sr) * (size_t)K + swz * 8;
    char* lA = (char*)As + wave * 1024;
    char* lB = (char*)Bs + wave * 1024;

    for (int k0 = 0; k0 < K; k0 += 64) {
        #pragma unroll
        for (int i = 0; i < 4; i++) {
            GLD_LDS16(ag + (size_t)(i * 32) * K + k0, lA + i * 4096);
            GLD_LDS16(bg + (size_t)(i * 32) * K + k0, lB + i * 4096);
        }
        __syncthreads();

        half8 af[2][4], bf[2][4];
        #pragma unroll
        for (int kk = 0; kk < 2; kk++) {
            #pragma unroll
            for (int mf = 0; mf < 4; mf++)
                af[kk][mf] = *(const half8*)&As[(wm + mf * 16 + l16) * 64
                                 + (((kk * 4 + quad) ^ (l16 & 7)) * 8)];
            #pragma unroll
            for (int nf = 0; nf < 4; nf++)
                bf[kk][nf] = *(const half8*)&Bs[(wn + nf * 16 + l16) * 64
                                 + (((kk * 4 + quad) ^ (l16 & 7)) * 8)];
        }

        #pragma unroll
        for (int kk = 0; kk < 2; kk++)
            #pragma unroll
            for (int mf = 0; mf < 4; mf++)
                #pragma unroll
                for (int nf = 0; nf < 4; nf++)
                    acc[mf][nf] = __builtin_amdgcn_mfma_f32_16x16x32_f16(
                        bf[kk][nf], af[kk][mf], acc[mf][nf], 0, 0, 0);
        __syncthreads();
    }

    #pragma unroll
    for (int mf = 0; mf < 4; mf++) {
        size_t tok = m0 + wm + mf * 16 + l16;
        #pragma unroll
        for (int nf = 0; nf < 4; nf++)
            *(floatx4*)(C + tok * N + n0 + wn + nf * 16 + quad * 4) = acc[mf][nf];
    }
}

// ---------------------------------------------------------------------------
extern "C" void kernel_launch(void* const* d_in, const int* in_sizes, int n_in,
                              void* d_out, int out_size, void* d_ws, size_t ws_size,
                              hipStream_t stream) {
    const float* x     = (const float*)d_in[0];
    const float* ln_g  = (const float*)d_in[1];
    const float* q_g   = (const float*)d_in[2];
    const float* k_g   = (const float*)d_in[3];
    const float* w_qkv = (const float*)d_in[4];
    const float* w_out = (const float*)d_in[5];
    float* out = (float*)d_out;

    // workspace (88 MB):
    //   [0,16)  xn   [16,22) wqkvT  [22,24) woutT
    //   [24,40) qf   [40,56) kf     [56,72) vt    [72,88) obuf
    char* base = (char*)d_ws;
    _Float16* xn    = (_Float16*)(base);
    _Float16* wqkvT = (_Float16*)(base + (16ull << 20));
    _Float16* woutT = (_Float16*)(base + (22ull << 20));
    _Float16* qf    = (_Float16*)(base + (24ull << 20));
    _Float16* kf    = (_Float16*)(base + (40ull << 20));
    _Float16* vt    = (_Float16*)(base + (56ull << 20));
    _Float16* obuf  = (_Float16*)(base + (72ull << 20));

    lnw_kernel<<<ROWS + 4096, 256, 0, stream>>>(x, ln_g, w_qkv, w_out,
                                                xn, wqkvT, woutT);

    dim3 g1(QKVW / 128, ROWS / 128);   // 24 x 64 = 1536 blocks
    hgemm_qkv<<<g1, 256, 0, stream>>>(xn, wqkvT, q_g, k_g, qf, kf, vt);

    flash_kernel<<<NB * HEADS * (NSEQ / 128), 256, 0, stream>>>(qf, kf, vt, obuf);

    dim3 g2(DIMX / 128, ROWS / 128);   // 8 x 64 = 512 blocks
    hgemm_out<<<g2, 256, 0, stream>>>(obuf, woutT, out);
}

// Round 10
// 243.691 us; speedup vs baseline: 1.0845x; 1.0203x over previous
//
#include <hip/hip_runtime.h>
#include <hip/hip_bf16.h>
#include <math.h>

#define DIMX   1024
#define HEADS  16
#define DH     64
#define NB     8
#define NSEQ   1024
#define ROWS   (NB * NSEQ)        // 8192
#define QKVW   (3 * DIMX)         // 3072
#define LOG2E  1.44269504088896f

typedef _Float16 half8 __attribute__((ext_vector_type(8)));
typedef _Float16 half4 __attribute__((ext_vector_type(4)));
typedef float floatx4 __attribute__((ext_vector_type(4)));

// async global->LDS, 16B per lane. lptr must be wave-uniform; HW adds lane*16.
#define GLD_LDS16(gptr, lptr) __builtin_amdgcn_global_load_lds( \
    (const __attribute__((address_space(1))) void*)(gptr),      \
    (__attribute__((address_space(3))) void*)(lptr), 16, 0, 0)

__device__ __forceinline__ float fexp2(float x) {
#if __has_builtin(__builtin_amdgcn_exp2f)
    return __builtin_amdgcn_exp2f(x);
#else
    return __expf(x * 0.69314718056f);
#endif
}

// ---------------------------------------------------------------------------
// Kernel 1: merged LayerNorm (blocks 0..8191) + weight transpose (8192..12287)
// ---------------------------------------------------------------------------
__global__ __launch_bounds__(256) void lnw_kernel(const float* __restrict__ x,
                                                  const float* __restrict__ gamma,
                                                  const float* __restrict__ Wq,
                                                  const float* __restrict__ Wo,
                                                  _Float16* __restrict__ xn,
                                                  _Float16* __restrict__ WqT,
                                                  _Float16* __restrict__ WoT) {
    __shared__ float tile[32][33];
    __shared__ float sbuf[4], ssbuf[4];
    int t = threadIdx.x;

    if (blockIdx.x < ROWS) {
        int row = blockIdx.x;
        const float* xr = x + (size_t)row * DIMX;
        _Float16* xo = xn + (size_t)row * DIMX;

        float4 v = ((const float4*)xr)[t];
        float s  = v.x + v.y + v.z + v.w;
        float ss = v.x*v.x + v.y*v.y + v.z*v.z + v.w*v.w;
        #pragma unroll
        for (int o = 32; o > 0; o >>= 1) {
            s  += __shfl_down(s, o);
            ss += __shfl_down(ss, o);
        }
        int lane = t & 63, wid = t >> 6;
        if (lane == 0) { sbuf[wid] = s; ssbuf[wid] = ss; }
        __syncthreads();
        if (t == 0) {
            float a = 0.f, b2 = 0.f;
            for (int i = 0; i < 4; i++) { a += sbuf[i]; b2 += ssbuf[i]; }
            sbuf[0] = a; ssbuf[0] = b2;
        }
        __syncthreads();
        float mean = sbuf[0] * (1.0f / DIMX);
        float var  = ssbuf[0] * (1.0f / DIMX) - mean * mean;
        float rstd = rsqrtf(var + 1e-5f);

        float4 g = ((const float4*)gamma)[t];
        half4 o;
        o.x = (_Float16)((v.x - mean) * rstd * g.x);
        o.y = (_Float16)((v.y - mean) * rstd * g.y);
        o.z = (_Float16)((v.z - mean) * rstd * g.z);
        o.w = (_Float16)((v.w - mean) * rstd * g.w);
        *(half4*)(xo + t * 4) = o;
    } else {
        int idx = blockIdx.x - ROWS;       // 0..4095
        int bx = idx & 127, by = idx >> 7; // 128 x 32
        const float* W; _Float16* WT; int N, n0;
        if (bx < 96) { W = Wq; WT = WqT; N = QKVW; n0 = bx * 32; }
        else         { W = Wo; WT = WoT; N = DIMX; n0 = (bx - 96) * 32; }
        int k0 = by * 32;
        int tx = t & 31, ty = t >> 5;      // 32 x 8
        #pragma unroll
        for (int i = 0; i < 32; i += 8)
            tile[ty + i][tx] = W[(size_t)(k0 + ty + i) * N + n0 + tx];
        __syncthreads();
        #pragma unroll
        for (int i = 0; i < 32; i += 8)
            WT[(size_t)(n0 + ty + i) * 1024 + k0 + tx] = (_Float16)tile[tx][ty + i];
    }
}

// ---------------------------------------------------------------------------
// Kernel 2: fused QKV GEMM + RMS(q,k) + per-head repack + V-transpose-store.
// (unchanged from R9: 128x128 tile, XCD-chunked bijective swizzle 8x192)
// ---------------------------------------------------------------------------
__global__ __launch_bounds__(256) void hgemm_qkv(const _Float16* __restrict__ A,
                                                 const _Float16* __restrict__ BT,
                                                 const float* __restrict__ qg,
                                                 const float* __restrict__ kg,
                                                 _Float16* __restrict__ qf,
                                                 _Float16* __restrict__ kf,
                                                 _Float16* __restrict__ vt) {
    __shared__ _Float16 As[128 * 64];
    __shared__ _Float16 Bs[128 * 64];
    const int K = DIMX;

    int t = threadIdx.x;
    int wave = t >> 6, lane = t & 63;
    int quad = lane >> 4, l16 = lane & 15;
    int wm = (wave >> 1) * 64;           // token offset within tile
    int wn = (wave & 1) * 64;            // feature offset within tile

    // XCD-chunked bijective swizzle: 1536 blocks = 8 XCDs x 192
    int p  = (int)(blockIdx.y * 24 + blockIdx.x);
    int sw = (p & 7) * 192 + (p >> 3);
    size_t m0 = (size_t)(sw / 24) * 128, n0 = (size_t)(sw % 24) * 128;

    floatx4 acc[4][4] = {};   // C^T frags: row=feature(nf,quad,r), col=token(mf,l16)

    int sr = t >> 3, sg = t & 7;
    int swz = sg ^ (sr & 7);
    const _Float16* ag = A  + (m0 + sr) * (size_t)K + swz * 8;
    const _Float16* bg = BT + (n0 + sr) * (size_t)K + swz * 8;
    char* lA = (char*)As + wave * 1024;
    char* lB = (char*)Bs + wave * 1024;

    for (int k0 = 0; k0 < K; k0 += 64) {
        #pragma unroll
        for (int i = 0; i < 4; i++) {
            GLD_LDS16(ag + (size_t)(i * 32) * K + k0, lA + i * 4096);
            GLD_LDS16(bg + (size_t)(i * 32) * K + k0, lB + i * 4096);
        }
        __syncthreads();

        half8 af[2][4], bf[2][4];
        #pragma unroll
        for (int kk = 0; kk < 2; kk++) {
            #pragma unroll
            for (int mf = 0; mf < 4; mf++)
                af[kk][mf] = *(const half8*)&As[(wm + mf * 16 + l16) * 64
                                 + (((kk * 4 + quad) ^ (l16 & 7)) * 8)];
            #pragma unroll
            for (int nf = 0; nf < 4; nf++)
                bf[kk][nf] = *(const half8*)&Bs[(wn + nf * 16 + l16) * 64
                                 + (((kk * 4 + quad) ^ (l16 & 7)) * 8)];
        }

        #pragma unroll
        for (int kk = 0; kk < 2; kk++)
            #pragma unroll
            for (int mf = 0; mf < 4; mf++)
                #pragma unroll
                for (int nf = 0; nf < 4; nf++)
                    acc[mf][nf] = __builtin_amdgcn_mfma_f32_16x16x32_f16(
                        bf[kk][nf], af[kk][mf], acc[mf][nf], 0, 0, 0);
        __syncthreads();
    }

    // epilogue: which = 0:q 1:k 2:v (block-uniform)
    int which = (int)(n0 >> 10);
    int nloc  = ((int)n0 & 1023) + wn;   // feature offset within q/k/v
    int h = nloc >> 6;

    if (which < 2) {
        const float* g = (which == 0) ? qg : kg;
        float emul = (which == 0) ? LOG2E : 1.0f;
        _Float16* dstbuf = (which == 0) ? qf : kf;
        #pragma unroll
        for (int mf = 0; mf < 4; mf++) {
            size_t tok = m0 + wm + mf * 16 + l16;
            int b = (int)(tok >> 10), ntk = (int)(tok & 1023);
            _Float16* dst = dstbuf + (((size_t)(b * 16 + h)) * 1024 + ntk) * 64;
            float ss = 0.f;
            #pragma unroll
            for (int nf = 0; nf < 4; nf++)
                #pragma unroll
                for (int r = 0; r < 4; r++) ss += acc[mf][nf][r] * acc[mf][nf][r];
            ss += __shfl_xor(ss, 16);
            ss += __shfl_xor(ss, 32);
            float scale = 8.0f * emul / fmaxf(sqrtf(ss), 1e-12f);
            #pragma unroll
            for (int nf = 0; nf < 4; nf++) {
                half4 ph;
                #pragma unroll
                for (int r = 0; r < 4; r++)
                    ph[r] = (_Float16)(acc[mf][nf][r] * scale *
                                       g[h * 64 + nf * 16 + quad * 4 + r]);
                *(half4*)(dst + nf * 16 + quad * 4) = ph;
            }
        }
    } else {
        // V: direct transposed store. vt[((bh*16+nt)*64 + d)*64 + tl]
        #pragma unroll
        for (int mf = 0; mf < 4; mf++) {
            size_t tok = m0 + wm + mf * 16 + l16;
            int b = (int)(tok >> 10), ntk = (int)(tok & 1023);
            int nt = ntk >> 6;
            _Float16* vd = vt + ((size_t)((b * 16 + h) * 16 + nt) * 64) * 64
                              + mf * 16 + l16;
            #pragma unroll
            for (int nf = 0; nf < 4; nf++)
                #pragma unroll
                for (int r = 0; r < 4; r++)
                    vd[(size_t)(nf * 16 + quad * 4 + r) * 64] =
                        (_Float16)acc[mf][nf][r];
        }
    }
}

// ---------------------------------------------------------------------------
// Kernel 3: flash attention (unchanged; bh-major mapping already XCD-optimal)
// ---------------------------------------------------------------------------
__global__ __launch_bounds__(256, 3) void flash_kernel(const _Float16* __restrict__ qf,
                                                       const _Float16* __restrict__ kf,
                                                       const _Float16* __restrict__ vt,
                                                       _Float16* __restrict__ obuf) {
    __shared__ _Float16 Ks[2][64 * 64];    // [buf][kcol][dh], group-swizzled
    __shared__ _Float16 VTs[2][64 * 64];   // [buf][dh][kcol], group-swizzled
    __shared__ _Float16 Ps[4][16][68];     // per-wave P^T [qrow][kcol]

    int t = threadIdx.x;
    int wave = t >> 6, lane = t & 63;
    int quad = lane >> 4, l16 = lane & 15;
    int bh = blockIdx.x & 127, qt = blockIdx.x >> 7;

    const _Float16* qb = qf + ((size_t)bh * 1024 + qt * 128) * 64;
    const _Float16* kb = kf + (size_t)bh * 65536;
    const _Float16* vb = vt + (size_t)bh * 65536;

    half8 aq[2][2];
    #pragma unroll
    for (int st = 0; st < 2; st++) {
        const _Float16* qrow = qb + (wave * 32 + st * 16 + l16) * 64;
        aq[st][0] = *(const half8*)(qrow + quad * 8);
        aq[st][1] = *(const half8*)(qrow + 32 + quad * 8);
    }

    floatx4 o[2][4] = {};
    float m_i[2] = {-INFINITY, -INFINITY};
    float l_i[2] = {0.f, 0.f};

    int sr = t >> 3;
    int sg = t & 7;
    int swz = sg ^ (sr & 7);

    // prologue: tile 0 -> buffer 0
    #pragma unroll
    for (int i = 0; i < 2; i++) {
        GLD_LDS16(kb + (i * 32 + sr) * 64 + swz * 8, (char*)Ks[0]  + wave * 1024 + i * 4096);
        GLD_LDS16(vb + (i * 32 + sr) * 64 + swz * 8, (char*)VTs[0] + wave * 1024 + i * 4096);
    }

    for (int kt = 0; kt < 16; kt++) {
        int cur = kt & 1;
        __syncthreads();   // drains cur's DMA (in flight for a full compute phase)

        if (kt < 15) {
            const _Float16* kn = kb + (size_t)(kt + 1) * 4096;
            const _Float16* vn = vb + (size_t)(kt + 1) * 4096;
            #pragma unroll
            for (int i = 0; i < 2; i++) {
                GLD_LDS16(kn + (i * 32 + sr) * 64 + swz * 8,
                          (char*)Ks[cur ^ 1]  + wave * 1024 + i * 4096);
                GLD_LDS16(vn + (i * 32 + sr) * 64 + swz * 8,
                          (char*)VTs[cur ^ 1] + wave * 1024 + i * 4096);
            }
        }

        #pragma unroll
        for (int st = 0; st < 2; st++) {
            // S^T = K Q^T (log2-domain scores; qf pre-scaled by LOG2E)
            floatx4 sc[4] = {};
            #pragma unroll
            for (int kc = 0; kc < 2; kc++) {
                #pragma unroll
                for (int nf = 0; nf < 4; nf++) {
                    half8 ak = *(const half8*)&Ks[cur][(nf * 16 + l16) * 64
                                    + (((kc * 4 + quad) ^ (l16 & 7)) * 8)];
                    sc[nf] = __builtin_amdgcn_mfma_f32_16x16x32_f16(
                        ak, aq[st][kc], sc[nf], 0, 0, 0);
                }
            }

            // online softmax (base-2): lane owns one q-row
            float mx = sc[0][0];
            #pragma unroll
            for (int nf = 0; nf < 4; nf++)
                #pragma unroll
                for (int r = 0; r < 4; r++) mx = fmaxf(mx, sc[nf][r]);
            mx = fmaxf(mx, __shfl_xor(mx, 16));
            mx = fmaxf(mx, __shfl_xor(mx, 32));
            if (mx > m_i[st]) {
                float alpha = fexp2(m_i[st] - mx);
                l_i[st] *= alpha;
                #pragma unroll
                for (int nf = 0; nf < 4; nf++) o[st][nf] *= alpha;
                m_i[st] = mx;
            }
            float mcur = m_i[st];
            float psum = 0.f;
            #pragma unroll
            for (int nf = 0; nf < 4; nf++)
                #pragma unroll
                for (int r = 0; r < 4; r++) {
                    float p = fexp2(sc[nf][r] - mcur);
                    sc[nf][r] = p;
                    psum += p;
                }
            l_i[st] += psum;

            // P^T -> LDS (b64 writes; stride 68 elems = conflict-free)
            #pragma unroll
            for (int nf = 0; nf < 4; nf++) {
                half4 p4;
                #pragma unroll
                for (int r = 0; r < 4; r++) p4[r] = (_Float16)sc[nf][r];
                *(half4*)&Ps[wave][l16][nf * 16 + quad * 4] = p4;
            }

            // O^T += V^T P^T
            #pragma unroll
            for (int kc = 0; kc < 2; kc++) {
                half4 p0 = *(const half4*)&Ps[wave][l16][kc * 32 + quad * 8];
                half4 p1 = *(const half4*)&Ps[wave][l16][kc * 32 + quad * 8 + 4];
                half8 bp;
                #pragma unroll
                for (int j = 0; j < 4; j++) { bp[j] = p0[j]; bp[4 + j] = p1[j]; }
                #pragma unroll
                for (int nf = 0; nf < 4; nf++) {
                    half8 av = *(const half8*)&VTs[cur][(nf * 16 + l16) * 64
                                    + (((kc * 4 + quad) ^ (l16 & 7)) * 8)];
                    o[st][nf] = __builtin_amdgcn_mfma_f32_16x16x32_f16(
                        av, bp, o[st][nf], 0, 0, 0);
                }
            }
        }
    }

    int b = bh >> 4, h = bh & 15;
    #pragma unroll
    for (int st = 0; st < 2; st++) {
        float lsum = l_i[st];
        lsum += __shfl_xor(lsum, 16);
        lsum += __shfl_xor(lsum, 32);
        float inv = 1.0f / lsum;
        size_t row = (size_t)b * NSEQ + qt * 128 + wave * 32 + st * 16 + l16;
        #pragma unroll
        for (int nf = 0; nf < 4; nf++) {
            half4 o4;
            #pragma unroll
            for (int r = 0; r < 4; r++) o4[r] = (_Float16)(o[st][nf][r] * inv);
            *(half4*)(obuf + row * 1024 + h * 64 + nf * 16 + quad * 4) = o4;
        }
    }
}

// ---------------------------------------------------------------------------
// Kernel 4: out-projection GEMM, fp32 out.
// NEW this round: tile 64M x 128N -> grid 8 x 128 = 1024 blocks = 4+/CU
// (was 512 = 2/CU; restores the cross-block overlap mechanism that gives
// hgemm_qkv its throughput). LDS 24 KB -> 6 blocks/CU ceiling; all blocks
// co-resident. XCD-chunked bijective swizzle 1024 = 8 x 128 (per-XCD A
// 2 MB + B 2 MB = 4 MB = per-XCD L2).
// ---------------------------------------------------------------------------
__global__ __launch_bounds__(256) void hgemm_out(const _Float16* __restrict__ A,
                                                 const _Float16* __restrict__ BT,
                                                 float* __restrict__ C) {
    __shared__ _Float16 As[64 * 64];
    __shared__ _Float16 Bs[128 * 64];
    const int K = DIMX, N = DIMX;

    int t = threadIdx.x;
    int wave = t >> 6, lane = t & 63;
    int quad = lane >> 4, l16 = lane & 15;
    int wm = (wave >> 1) * 32, wn = (wave & 1) * 64;   // per-wave 32 x 64

    // XCD-chunked bijective swizzle: 1024 blocks = 8 XCDs x 128
    // (16 M-panels x 8 N-tiles each, N-fastest within the chunk)
    int p  = (int)(blockIdx.y * 8 + blockIdx.x);
    int sw = (p & 7) * 128 + (p >> 3);
    size_t m0 = (size_t)(sw >> 3) * 64, n0 = (size_t)(sw & 7) * 128;

    floatx4 acc[2][4] = {};

    int sr = t >> 3, sg = t & 7;
    int swz = sg ^ (sr & 7);
    const _Float16* ag = A  + (m0 + sr) * (size_t)K + swz * 8;
    const _Float16* bg = BT + (n0 + sr) * (size_t)K + swz * 8;
    char* lA = (char*)As + wave * 1024;
    char* lB = (char*)Bs + wave * 1024;

    for (int k0 = 0; k0 < K; k0 += 64) {
        #pragma unroll
        for (int i = 0; i < 2; i++)
            GLD_LDS16(ag + (size_t)(i * 32) * K + k0, lA + i * 4096);
        #pragma unroll
        for (int i = 0; i < 4; i++)
            GLD_LDS16(bg + (size_t)(i * 32) * K + k0, lB + i * 4096);
        __syncthreads();

        half8 af[2][2], bf[2][4];
        #pragma unroll
        for (int kk = 0; kk < 2; kk++) {
            #pragma unroll
            for (int mf = 0; mf < 2; mf++)
                af[kk][mf] = *(const half8*)&As[(wm + mf * 16 + l16) * 64
                                 + (((kk * 4 + quad) ^ (l16 & 7)) * 8)];
            #pragma unroll
            for (int nf = 0; nf < 4; nf++)
                bf[kk][nf] = *(const half8*)&Bs[(wn + nf * 16 + l16) * 64
                                 + (((kk * 4 + quad) ^ (l16 & 7)) * 8)];
        }

        #pragma unroll
        for (int kk = 0; kk < 2; kk++)
            #pragma unroll
            for (int mf = 0; mf < 2; mf++)
                #pragma unroll
                for (int nf = 0; nf < 4; nf++)
                    acc[mf][nf] = __builtin_amdgcn_mfma_f32_16x16x32_f16(
                        bf[kk][nf], af[kk][mf], acc[mf][nf], 0, 0, 0);
        __syncthreads();
    }

    #pragma unroll
    for (int mf = 0; mf < 2; mf++) {
        size_t tok = m0 + wm + mf * 16 + l16;
        #pragma unroll
        for (int nf = 0; nf < 4; nf++)
            *(floatx4*)(C + tok * N + n0 + wn + nf * 16 + quad * 4) = acc[mf][nf];
    }
}

// ---------------------------------------------------------------------------
extern "C" void kernel_launch(void* const* d_in, const int* in_sizes, int n_in,
                              void* d_out, int out_size, void* d_ws, size_t ws_size,
                              hipStream_t stream) {
    const float* x     = (const float*)d_in[0];
    const float* ln_g  = (const float*)d_in[1];
    const float* q_g   = (const float*)d_in[2];
    const float* k_g   = (const float*)d_in[3];
    const float* w_qkv = (const float*)d_in[4];
    const float* w_out = (const float*)d_in[5];
    float* out = (float*)d_out;

    // workspace (88 MB):
    //   [0,16)  xn   [16,22) wqkvT  [22,24) woutT
    //   [24,40) qf   [40,56) kf     [56,72) vt    [72,88) obuf
    char* base = (char*)d_ws;
    _Float16* xn    = (_Float16*)(base);
    _Float16* wqkvT = (_Float16*)(base + (16ull << 20));
    _Float16* woutT = (_Float16*)(base + (22ull << 20));
    _Float16* qf    = (_Float16*)(base + (24ull << 20));
    _Float16* kf    = (_Float16*)(base + (40ull << 20));
    _Float16* vt    = (_Float16*)(base + (56ull << 20));
    _Float16* obuf  = (_Float16*)(base + (72ull << 20));

    lnw_kernel<<<ROWS + 4096, 256, 0, stream>>>(x, ln_g, w_qkv, w_out,
                                                xn, wqkvT, woutT);

    dim3 g1(QKVW / 128, ROWS / 128);   // 24 x 64 = 1536 blocks
    hgemm_qkv<<<g1, 256, 0, stream>>>(xn, wqkvT, q_g, k_g, qf, kf, vt);

    flash_kernel<<<NB * HEADS * (NSEQ / 128), 256, 0, stream>>>(qf, kf, vt, obuf);

    dim3 g2(DIMX / 128, ROWS / 64);    // 8 x 128 = 1024 blocks
    hgemm_out<<<g2, 256, 0, stream>>>(obuf, woutT, out);
}